// Round 7
// baseline (281.296 us; speedup 1.0000x reference)
//
#include <hip/hip_runtime.h>
#include <hip/hip_bf16.h>

// ---------------- problem constants ----------------
// B=2 T2=9 T3=27 T1=243 P=17 K2=9 C=128
// CH = {48,96,192,384}, HW = {(96,72),(48,36),(24,18),(12,9)}, N=18
static constexpr int NQ_SIZE = 9517824;
static constexpr int NV_SIZE = 1057536;
static constexpr int NPOS    = 74358;   // 486*153 sampling points
static constexpr int M_CONV  = 8262;    // 2*243*17 rows of the conv GEMM

// E-map (projected feature, bf16, channels-last [n,h,w,128]) element offsets in ws
static constexpr long E0_OFF = 0;
static constexpr long E1_OFF = 15925248;            // 18*96*72*128
static constexpr long E2_OFF = E1_OFF + 3981312;    // 18*48*36*128
static constexpr long E3_OFF = E2_OFF + 995328;     // 18*24*18*128
static constexpr long E_END  = E3_OFF + 248832;     // 18*12*9*128  -> 21,150,720 elems

// prep kernel block-range segmentation (long-serial levels first)
static constexpr int SEG_F3  = 36;            // 2 tiles x 18
static constexpr int SEG_F2  = SEG_F3 + 126;  // 7 x 18
static constexpr int SEG_F1  = SEG_F2 + 486;  // 27 x 18
static constexpr int SEG_F0  = SEG_F1 + 1944; // 108 x 18
static constexpr int SEG_CT  = SEG_F0 + 576;  // convT2: 147456/256
static constexpr int SEG_SP  = SEG_CT + 486;  // sampos
static constexpr int PREP_GRID = SEG_SP;      // 3654

typedef __attribute__((ext_vector_type(8))) short short8;   // 8 bf16 (4 VGPRs)
typedef __attribute__((ext_vector_type(4))) float floatx4;

__device__ __forceinline__ float bf2f(unsigned short u) {
    union { unsigned int i; float f; } v; v.i = ((unsigned)u) << 16; return v.f;
}
__device__ __forceinline__ unsigned short f2bf_rne(float f) {
    union { float f; unsigned int i; } v; v.f = f;
    unsigned int u = v.i;
    u += 0x7fffu + ((u >> 16) & 1u);
    return (unsigned short)(u >> 16);
}
__device__ __forceinline__ short8 pack8(const float* t) {
    union { unsigned short u[8]; short8 s; } r;
    #pragma unroll
    for (int i = 0; i < 8; ++i) r.u[i] = f2bf_rne(t[i]);
    return r.s;
}

// ---------------- fused prep kernel ----------------
// blocks [0,SEG_F0): projection GEMMs via bf16 MFMA, BOTH operands
//      direct-to-register, NO LDS, NO barriers:
//        E_l[n,s,o] = sum_c f_l[n,c,s] * we_l[o,c]
//      Operand roles: A = we (m-dim = o), B = f (n-dim = s).
//      Per wave: 16 s-values (lane&15), all 128 o (8 MFMA tiles), BK=32.
//      D layout (verified): col=lane&15 -> s, row=quad*4+r -> o within tile,
//      so each lane stores 4 consecutive channels = one uint2.
// blocks [SEG_F0,SEG_CT): convT2[o*1152+(k2*128+c)] = bf16(conv_w[o*1152+c*9+k2])
// blocks [SEG_CT,SEG_SP): sampling positions
__global__ __launch_bounds__(256) void prep_k(
    const float* __restrict__ f0, const float* __restrict__ f1,
    const float* __restrict__ f2, const float* __restrict__ f3,
    const float* __restrict__ we0, const float* __restrict__ we1,
    const float* __restrict__ we2, const float* __restrict__ we3,
    const float* __restrict__ conv_w, unsigned short* __restrict__ convT2,
    const float* __restrict__ query, const float* __restrict__ value,
    const float* __restrict__ key,
    const float* __restrict__ w_off, const float* __restrict__ b_off,
    const float* __restrict__ w_attn, const float* __restrict__ b_attn,
    float* __restrict__ samp, unsigned short* __restrict__ Ebase)
{
    const int bid = blockIdx.x;
    const int tid = threadIdx.x;

    if (bid < SEG_F0) {
        const float* A; const float* W; unsigned short* Eo;
        int M, K, m0;     // M = spatial size (s), K = channels, m0 = s-tile base
        if (bid < SEG_F3) {
            int n = bid >> 1, t = bid & 1;
            M = 108; K = 384; A = f3 + (long)n * 384 * 108; W = we3;
            Eo = Ebase + E3_OFF + (long)n * 108 * 128; m0 = t * 64;
        } else if (bid < SEG_F2) {
            int r = bid - SEG_F3; int n = r / 7, t = r - n * 7;
            M = 432; K = 192; A = f2 + (long)n * 192 * 432; W = we2;
            Eo = Ebase + E2_OFF + (long)n * 432 * 128; m0 = t * 64;
        } else if (bid < SEG_F1) {
            int r = bid - SEG_F2; int n = r / 27, t = r - n * 27;
            M = 1728; K = 96; A = f1 + (long)n * 96 * 1728; W = we1;
            Eo = Ebase + E1_OFF + (long)n * 1728 * 128; m0 = t * 64;
        } else {
            int r = bid - SEG_F1; int n = r / 108, t = r - n * 108;
            M = 6912; K = 48; A = f0 + (long)n * 48 * 6912; W = we0;
            Eo = Ebase + E0_OFF + (long)n * 6912 * 128; m0 = t * 64;
        }

        const int lane = tid & 63;
        const int wave = tid >> 6;
        const int l15  = lane & 15;
        const int quad = lane >> 4;
        const int sl   = m0 + wave * 16 + l15;     // this lane's s (B/N side, D col)
        const bool sval = (sl < M);
        const int scl  = sval ? sl : (M - 1);      // clamped for loads

        floatx4 acc[8];
        #pragma unroll
        for (int t = 0; t < 8; ++t) acc[t] = (floatx4){0.f, 0.f, 0.f, 0.f};

        const int nkt = (K + 31) >> 5;
        for (int kt = 0; kt < nkt; ++kt) {
            const int kq = kt * 32 + quad * 8;     // this lane's k base (K%8==0)
            const bool kv = (kq < K);
            // B fragment: f[kq+j][scl], j stride M (lanes coalesced over s)
            float bfv[8] = {0,0,0,0,0,0,0,0};
            if (kv) {
                const float* bp = A + (long)kq * M + scl;
                #pragma unroll
                for (int j = 0; j < 8; ++j) bfv[j] = bp[(long)j * M];
            }
            short8 bfr = pack8(bfv);
            // A fragments: we[t*16+l15][kq..kq+7] contiguous; 8 MFMAs
            #pragma unroll
            for (int t = 0; t < 8; ++t) {
                float afv[8] = {0,0,0,0,0,0,0,0};
                if (kv) {
                    const float* ap = W + (long)(t * 16 + l15) * K + kq;
                    float4 w0 = *(const float4*)ap;
                    float4 w1 = *(const float4*)(ap + 4);
                    afv[0] = w0.x; afv[1] = w0.y; afv[2] = w0.z; afv[3] = w0.w;
                    afv[4] = w1.x; afv[5] = w1.y; afv[6] = w1.z; afv[7] = w1.w;
                }
                short8 af = pack8(afv);
                acc[t] = __builtin_amdgcn_mfma_f32_16x16x32_bf16(af, bfr, acc[t], 0, 0, 0);
            }
        }

        // store: lane -> E[sl][t*16 + quad*4 + r], 4 consecutive u16 per tile
        if (sval) {
            unsigned short* ep = Eo + (long)sl * 128;
            #pragma unroll
            for (int t = 0; t < 8; ++t) {
                unsigned short tt[4] = {f2bf_rne(acc[t][0]), f2bf_rne(acc[t][1]),
                                        f2bf_rne(acc[t][2]), f2bf_rne(acc[t][3])};
                *(uint2*)(ep + t * 16 + quad * 4) = *(const uint2*)tt;
            }
        }
    } else if (bid < SEG_CT) {
        // ---- convT2 transpose+cast ----
        int idx = (bid - SEG_F0) * 256 + tid;
        if (idx < 147456) {
            int o = idx / 1152, kk = idx - o * 1152;
            int k2 = kk >> 7, c = kk & 127;
            convT2[idx] = f2bf_rne(conv_w[o * 1152 + c * 9 + k2]);
        }
    } else {
        // ---- sampling positions, one (b,t1) per block ----
        const int bt1 = bid - SEG_CT;      // 0..485
        const int b  = bt1 / 243, t1 = bt1 - b * 243;
        const int t2 = t1 / 27,  t3 = t1 - t2 * 27;
        const int n  = b * 9 + t2;
        __shared__ float logit[17][2];
        __shared__ float aw[17][2];

        if (tid < 34) {
            int p = tid >> 1, o = tid & 1;
            const float* vrow = value + ((long)bt1 * 17 + p) * 128;
            const float* wrow = w_attn + o * 128;
            float s = 0.f;
            for (int c = 0; c < 128; c += 4) {
                float4 v = *(const float4*)(vrow + c);
                float4 w = *(const float4*)(wrow + c);
                s += v.x * w.x + v.y * w.y + v.z * w.z + v.w * w.w;
            }
            logit[p][o] = s + b_attn[o];
        }
        __syncthreads();
        if (tid < 17) {
            float l0 = logit[tid][0], l1 = logit[tid][1];
            float mx = fmaxf(l0, l1);
            float e0 = expf(l0 - mx), e1 = expf(l1 - mx);
            float inv = 1.f / (e0 + e1);
            aw[tid][0] = e0 * inv; aw[tid][1] = e1 * inv;
        }
        __syncthreads();
        for (int j = tid; j < 306; j += 256) {
            int q = j >> 1, o = j & 1;
            const float* qrow = query + ((long)bt1 * 153 + q) * 128;
            const float* wrow = w_off + o * 128;
            float s = 0.f;
            for (int c = 0; c < 128; c += 4) {
                float4 v = *(const float4*)(qrow + c);
                float4 w = *(const float4*)(wrow + c);
                s += v.x * w.x + v.y * w.y + v.z * w.z + v.w * w.w;
            }
            float off = tanhf(s + b_off[o]);
            float sp = off * aw[q % 17][o];
            long kidx = (((long)n * 27 + t3) * 153 + q) * 2 + o;
            samp[kidx] = key[kidx] + sp;
        }
    }
}

// ---------------- gather + mean + blend -> new_query ----------------
// 8 positions/block, 32 lanes/position, 4 channels/lane (float4).
__global__ __launch_bounds__(256) void gather_k(
    const unsigned short* __restrict__ Ebase,
    const float* __restrict__ samp, const float* __restrict__ query,
    const float* __restrict__ be0, const float* __restrict__ be1,
    const float* __restrict__ be2, const float* __restrict__ be3,
    float* __restrict__ nq)
{
    const int tid = threadIdx.x;
    const int pos = blockIdx.x * 8 + (tid >> 5);
    if (pos >= NPOS) return;
    const int c4 = (tid & 31) << 2;
    const int bt1 = pos / 153, q = pos - bt1 * 153;
    const int b  = bt1 / 243, t1 = bt1 - b * 243;
    const int t2 = t1 / 27,  t3 = t1 - t2 * 27;
    const int n  = b * 9 + t2;
    const long sbase = (((long)n * 27 + t3) * 153 + q) * 2;
    const float gx = samp[sbase], gy = samp[sbase + 1];

    float ax = 0.f, ay = 0.f, az = 0.f, aww = 0.f;
    const long Eoffs[4] = {E0_OFF, E1_OFF, E2_OFF, E3_OFF};
    const int Hs[4] = {96, 48, 24, 12}, Wd[4] = {72, 36, 18, 9};
    #pragma unroll
    for (int l = 0; l < 4; ++l) {
        const int H = Hs[l], W = Wd[l];
        const unsigned short* E = Ebase + Eoffs[l] + (long)n * H * W * 128 + c4;
        float ix = ((gx + 1.f) * (float)W - 1.f) * 0.5f;
        float iy = ((gy + 1.f) * (float)H - 1.f) * 0.5f;
        float fx0 = floorf(ix), fy0 = floorf(iy);
        int x0 = (int)fx0, y0 = (int)fy0;
        int x1 = x0 + 1, y1 = y0 + 1;
        float wx1 = ix - fx0, wx0 = 1.f - wx1;
        float wy1 = iy - fy0, wy0 = 1.f - wy1;
        float w00 = wy0 * wx0, w01 = wy0 * wx1, w10 = wy1 * wx0, w11 = wy1 * wx1;
        bool vy0 = (unsigned)y0 < (unsigned)H, vy1 = (unsigned)y1 < (unsigned)H;
        bool vx0 = (unsigned)x0 < (unsigned)W, vx1 = (unsigned)x1 < (unsigned)W;
        if (vy0 && vx0) { ushort4 v = *(const ushort4*)(E + ((long)y0 * W + x0) * 128);
            ax = fmaf(w00, bf2f(v.x), ax); ay = fmaf(w00, bf2f(v.y), ay);
            az = fmaf(w00, bf2f(v.z), az); aww = fmaf(w00, bf2f(v.w), aww); }
        if (vy0 && vx1) { ushort4 v = *(const ushort4*)(E + ((long)y0 * W + x1) * 128);
            ax = fmaf(w01, bf2f(v.x), ax); ay = fmaf(w01, bf2f(v.y), ay);
            az = fmaf(w01, bf2f(v.z), az); aww = fmaf(w01, bf2f(v.w), aww); }
        if (vy1 && vx0) { ushort4 v = *(const ushort4*)(E + ((long)y1 * W + x0) * 128);
            ax = fmaf(w10, bf2f(v.x), ax); ay = fmaf(w10, bf2f(v.y), ay);
            az = fmaf(w10, bf2f(v.z), az); aww = fmaf(w10, bf2f(v.w), aww); }
        if (vy1 && vx1) { ushort4 v = *(const ushort4*)(E + ((long)y1 * W + x1) * 128);
            ax = fmaf(w11, bf2f(v.x), ax); ay = fmaf(w11, bf2f(v.y), ay);
            az = fmaf(w11, bf2f(v.z), az); aww = fmaf(w11, bf2f(v.w), aww); }
    }
    float bsx = be0[c4]     + be1[c4]     + be2[c4]     + be3[c4];
    float bsy = be0[c4 + 1] + be1[c4 + 1] + be2[c4 + 1] + be3[c4 + 1];
    float bsz = be0[c4 + 2] + be1[c4 + 2] + be2[c4 + 2] + be3[c4 + 2];
    float bsw = be0[c4 + 3] + be1[c4 + 3] + be2[c4 + 3] + be3[c4 + 3];
    float mx = 0.25f * (ax + bsx), my = 0.25f * (ay + bsy);
    float mz = 0.25f * (az + bsz), mw = 0.25f * (aww + bsw);
    const long qi = ((long)bt1 * 153 + q) * 128 + c4;
    float4 qv = *(const float4*)(query + qi);
    float4 o;
    o.x = 0.1f * mx + 0.9f * qv.x;
    o.y = 0.1f * my + 0.9f * qv.y;
    o.z = 0.1f * mz + 0.9f * qv.z;
    o.w = 0.1f * mw + 0.9f * qv.w;
    *(float4*)(nq + qi) = o;
}

// ---------------- conv GEMM via bf16 MFMA ----------------
// nv[m][o] = sum_kk nq[m*1152+kk] * convT2[o][kk] + conv_b[o]
// grid (259 m-tiles, 2 n-tiles); block 256 = 4 waves (2x2);
// tile M=32 x N=64, BK=32; register double-buffer. 518 blocks for latency hiding.
__global__ __launch_bounds__(256) void conv_mfma_k(
    const float* __restrict__ nq, const unsigned short* __restrict__ convT2,
    const float* __restrict__ conv_b, float* __restrict__ nv)
{
    __shared__ unsigned short As[32][40];   // [m][k] pad 32->40
    __shared__ unsigned short Bs[64][40];   // [n][k]

    const int tid  = threadIdx.x;
    const int lane = tid & 63;
    const int wave = tid >> 6;
    const int wm = (wave & 1) * 16;
    const int wn = (wave >> 1) * 32;
    const int m0 = blockIdx.x * 32;
    const int n0 = blockIdx.y * 64;
    const int l15  = lane & 15;
    const int quad = lane >> 4;

    floatx4 acc[2];
    acc[0] = (floatx4){0.f, 0.f, 0.f, 0.f};
    acc[1] = acc[0];

    const int am = tid >> 3;             // 0..31
    const int ak = (tid & 7) << 2;       // 0,4,..,28
    const int bn = tid >> 2;             // 0..63
    const int bk = (tid & 3) << 3;       // 0,8,16,24

    float4 a0; uint4 bv;
    auto fetch = [&](int k0) {
        a0 = (float4){0,0,0,0};
        int row = m0 + am;
        if (row < M_CONV)
            a0 = *(const float4*)(nq + (long)row * 1152 + k0 + ak);
        bv = *(const uint4*)(convT2 + (long)(n0 + bn) * 1152 + k0 + bk);
    };
    fetch(0);

    for (int k0 = 0; k0 < 1152; k0 += 32) {
        unsigned short t[4] = {f2bf_rne(a0.x), f2bf_rne(a0.y), f2bf_rne(a0.z), f2bf_rne(a0.w)};
        *(uint2*)&As[am][ak] = *(const uint2*)t;
        *(uint4*)&Bs[bn][bk] = bv;
        __syncthreads();
        if (k0 + 32 < 1152) fetch(k0 + 32);

        short8 af = *(const short8*)&As[wm + l15][quad * 8];
        #pragma unroll
        for (int nt = 0; nt < 2; ++nt) {
            short8 bf = *(const short8*)&Bs[wn + nt * 16 + l15][quad * 8];
            acc[nt] = __builtin_amdgcn_mfma_f32_16x16x32_bf16(af, bf, acc[nt], 0, 0, 0);
        }
        __syncthreads();
    }

    // epilogue: C/D layout col=lane&15, row=quad*4+r
    #pragma unroll
    for (int nt = 0; nt < 2; ++nt) {
        int col = n0 + wn + nt * 16 + l15;
        float bias = conv_b[col];
        #pragma unroll
        for (int r = 0; r < 4; ++r) {
            int row = m0 + wm + quad * 4 + r;
            if (row < M_CONV)
                nv[(long)row * 128 + col] = acc[nt][r] + bias;
        }
    }
}

extern "C" void kernel_launch(void* const* d_in, const int* in_sizes, int n_in,
                              void* d_out, int out_size, void* d_ws, size_t ws_size,
                              hipStream_t stream) {
    const float* f0     = (const float*)d_in[0];
    const float* f1     = (const float*)d_in[1];
    const float* f2     = (const float*)d_in[2];
    const float* f3     = (const float*)d_in[3];
    const float* query  = (const float*)d_in[4];
    const float* key    = (const float*)d_in[5];
    const float* value  = (const float*)d_in[6];
    const float* w_off  = (const float*)d_in[7];
    const float* b_off  = (const float*)d_in[8];
    const float* w_attn = (const float*)d_in[9];
    const float* b_attn = (const float*)d_in[10];
    const float* we0    = (const float*)d_in[11];
    const float* be0    = (const float*)d_in[12];
    const float* we1    = (const float*)d_in[13];
    const float* be1    = (const float*)d_in[14];
    const float* we2    = (const float*)d_in[15];
    const float* be2    = (const float*)d_in[16];
    const float* we3    = (const float*)d_in[17];
    const float* be3    = (const float*)d_in[18];
    const float* conv_w = (const float*)d_in[19];
    const float* conv_b = (const float*)d_in[20];

    float* out  = (float*)d_out;
    float* nq   = out;                       // new_query
    float* nv   = out + NQ_SIZE;             // new_value
    float* samp = out + NQ_SIZE + NV_SIZE;   // sampling_positions

    // ws layout: E maps (bf16, 21,150,720) | convT2 (bf16, 147,456)
    unsigned short* Ebase  = (unsigned short*)d_ws;
    unsigned short* convT2 = Ebase + E_END;

    // 1. fused prep: projections (MFMA, barrier-free) + convT2 + sampling positions
    prep_k<<<PREP_GRID, 256, 0, stream>>>(
        f0, f1, f2, f3, we0, we1, we2, we3, conv_w, convT2,
        query, value, key, w_off, b_off, w_attn, b_attn, samp, Ebase);

    // 2. gather + mean + blend -> new_query (9295 blocks)
    gather_k<<<(NPOS + 7) / 8, 256, 0, stream>>>(Ebase, samp, query, be0, be1, be2, be3, nq);

    // 3. new_value GEMM via MFMA: M=8262, K=1152, N=128 (518 blocks)
    conv_mfma_k<<<dim3(259, 2), 256, 0, stream>>>(nq, convT2, conv_b, nv);
}

// Round 9
// 251.935 us; speedup vs baseline: 1.1165x; 1.1165x over previous
//
#include <hip/hip_runtime.h>
#include <hip/hip_bf16.h>

// ---------------- problem constants ----------------
// B=2 T2=9 T3=27 T1=243 P=17 K2=9 C=128
// CH = {48,96,192,384}, HW = {(96,72),(48,36),(24,18),(12,9)}, N=18
static constexpr int NQ_SIZE = 9517824;
static constexpr int NV_SIZE = 1057536;
static constexpr int NPOS    = 74358;   // 486*153 sampling points
static constexpr int M_CONV  = 8262;    // 2*243*17 rows of the conv GEMM

// E-map (projected feature, bf16, channels-last [n,h,w,128]) element offsets in ws
static constexpr long E0_OFF = 0;
static constexpr long E1_OFF = 15925248;            // 18*96*72*128
static constexpr long E2_OFF = E1_OFF + 3981312;    // 18*48*36*128
static constexpr long E3_OFF = E2_OFF + 995328;     // 18*24*18*128
static constexpr long E_END  = E3_OFF + 248832;     // 18*12*9*128  -> 21,150,720 elems

// prep kernel block-range segmentation (long-serial levels first)
static constexpr int SEG_F3  = 36;            // 2 tiles x 18
static constexpr int SEG_F2  = SEG_F3 + 126;  // 7 x 18
static constexpr int SEG_F1  = SEG_F2 + 486;  // 27 x 18
static constexpr int SEG_F0  = SEG_F1 + 1944; // 108 x 18
static constexpr int SEG_CT  = SEG_F0 + 576;  // convT2: 147456/256
static constexpr int SEG_SP  = SEG_CT + 486;  // sampos
static constexpr int PREP_GRID = SEG_SP;      // 3654

typedef __attribute__((ext_vector_type(8))) short short8;   // 8 bf16 (4 VGPRs)
typedef __attribute__((ext_vector_type(4))) float floatx4;

__device__ __forceinline__ float bf2f(unsigned short u) {
    union { unsigned int i; float f; } v; v.i = ((unsigned)u) << 16; return v.f;
}
__device__ __forceinline__ unsigned short f2bf_rne(float f) {
    union { float f; unsigned int i; } v; v.f = f;
    unsigned int u = v.i;
    u += 0x7fffu + ((u >> 16) & 1u);
    return (unsigned short)(u >> 16);
}
__device__ __forceinline__ short8 pack8(const float* t) {
    union { unsigned short u[8]; short8 s; } r;
    #pragma unroll
    for (int i = 0; i < 8; ++i) r.u[i] = f2bf_rne(t[i]);
    return r.s;
}

// ---------------- fused prep kernel ----------------
// blocks [0,SEG_F0): projection GEMMs via bf16 MFMA:
//      E_l[n,s,o] = sum_c f_l[n,c,s] * we_l[o,c]
//      A-operand = f fragment, direct global->VGPR (no LDS, no transpose).
//      B-operand = we, staged in LDS in 96-wide K-chunks ONCE. Row pad
//      96->104. IMPORTANT: every LDS cell of the chunk is ALWAYS written
//      (zeros beyond K) -- R8's skip-write left garbage that 0*NaN'd.
// blocks [SEG_F0,SEG_CT): convT2[o*1152+(k2*128+c)] = bf16(conv_w[o*1152+c*9+k2])
// blocks [SEG_CT,SEG_SP): sampling positions
__global__ __launch_bounds__(256) void prep_k(
    const float* __restrict__ f0, const float* __restrict__ f1,
    const float* __restrict__ f2, const float* __restrict__ f3,
    const float* __restrict__ we0, const float* __restrict__ we1,
    const float* __restrict__ we2, const float* __restrict__ we3,
    const float* __restrict__ conv_w, unsigned short* __restrict__ convT2,
    const float* __restrict__ query, const float* __restrict__ value,
    const float* __restrict__ key,
    const float* __restrict__ w_off, const float* __restrict__ b_off,
    const float* __restrict__ w_attn, const float* __restrict__ b_attn,
    float* __restrict__ samp, unsigned short* __restrict__ Ebase)
{
    const int bid = blockIdx.x;
    const int tid = threadIdx.x;

    if (bid < SEG_F0) {
        __shared__ unsigned short Bs[128][104];   // [o][k-chunk], pad 96->104

        const float* A; const float* W; unsigned short* Eo;
        int M, K, m0;
        if (bid < SEG_F3) {
            int n = bid >> 1, t = bid & 1;
            M = 108; K = 384; A = f3 + (long)n * 384 * 108; W = we3;
            Eo = Ebase + E3_OFF + (long)n * 108 * 128; m0 = t * 64;
        } else if (bid < SEG_F2) {
            int r = bid - SEG_F3; int n = r / 7, t = r - n * 7;
            M = 432; K = 192; A = f2 + (long)n * 192 * 432; W = we2;
            Eo = Ebase + E2_OFF + (long)n * 432 * 128; m0 = t * 64;
        } else if (bid < SEG_F1) {
            int r = bid - SEG_F2; int n = r / 27, t = r - n * 27;
            M = 1728; K = 96; A = f1 + (long)n * 96 * 1728; W = we1;
            Eo = Ebase + E1_OFF + (long)n * 1728 * 128; m0 = t * 64;
        } else {
            int r = bid - SEG_F1; int n = r / 108, t = r - n * 108;
            M = 6912; K = 48; A = f0 + (long)n * 48 * 6912; W = we0;
            Eo = Ebase + E0_OFF + (long)n * 6912 * 128; m0 = t * 64;
        }

        const int lane = tid & 63;
        const int wave = tid >> 6;
        const int l15  = lane & 15;
        const int quad = lane >> 4;
        const int mg   = m0 + wave * 16 + l15;   // global m row for this lane

        floatx4 acc[8];
        #pragma unroll
        for (int j = 0; j < 8; ++j) acc[j] = (floatx4){0.f, 0.f, 0.f, 0.f};

        // B staging: thread -> o = tid>>1 (0..127), col-half = (tid&1)*48
        const int so = tid >> 1;
        const int sh = (tid & 1) * 48;

        for (int c0 = 0; c0 < K; c0 += 96) {
            if (c0) __syncthreads();              // prior chunk fully consumed
            {
                const float* wp = W + (long)so * K + c0 + sh;
                #pragma unroll
                for (int i = 0; i < 6; ++i) {
                    float t8[8] = {0.f,0.f,0.f,0.f,0.f,0.f,0.f,0.f};
                    if (c0 + sh + i * 8 < K) {    // K%8==0 -> all 8 valid
                        float4 w0 = *(const float4*)(wp + i * 8);
                        float4 w1 = *(const float4*)(wp + i * 8 + 4);
                        t8[0]=w0.x; t8[1]=w0.y; t8[2]=w0.z; t8[3]=w0.w;
                        t8[4]=w1.x; t8[5]=w1.y; t8[6]=w1.z; t8[7]=w1.w;
                    }
                    unsigned short u[8];
                    #pragma unroll
                    for (int j = 0; j < 8; ++j) u[j] = f2bf_rne(t8[j]);
                    *(uint4*)&Bs[so][sh + i * 8] = *(const uint4*)u;
                }
            }
            __syncthreads();

            const int clen = (K - c0 < 96) ? (K - c0) : 96;
            for (int lk = 0; lk < clen; lk += 32) {
                const int kq = c0 + lk + quad * 8;
                float a_f[8];
                {
                    const float* ap = A + (long)kq * M + mg;
                    #pragma unroll
                    for (int j = 0; j < 8; ++j) {
                        a_f[j] = 0.f;
                        if (mg < M && kq + j < K) a_f[j] = ap[(long)j * M];
                    }
                }
                short8 af = pack8(a_f);
                #pragma unroll
                for (int nt = 0; nt < 8; ++nt) {
                    short8 bf = *(const short8*)&Bs[nt * 16 + l15][lk + quad * 8];
                    acc[nt] = __builtin_amdgcn_mfma_f32_16x16x32_bf16(af, bf, acc[nt], 0, 0, 0);
                }
            }
        }

        // epilogue: C/D col=lane&15 (o), row=quad*4+r (m within the wave's 16)
        #pragma unroll
        for (int nt = 0; nt < 8; ++nt) {
            int col = nt * 16 + l15;
            #pragma unroll
            for (int r = 0; r < 4; ++r) {
                int m = m0 + wave * 16 + quad * 4 + r;
                if (m < M)
                    Eo[(long)m * 128 + col] = f2bf_rne(acc[nt][r]);
            }
        }
    } else if (bid < SEG_CT) {
        // ---- convT2 transpose+cast ----
        int idx = (bid - SEG_F0) * 256 + tid;
        if (idx < 147456) {
            int o = idx / 1152, kk = idx - o * 1152;
            int k2 = kk >> 7, c = kk & 127;
            convT2[idx] = f2bf_rne(conv_w[o * 1152 + c * 9 + k2]);
        }
    } else {
        // ---- sampling positions, one (b,t1) per block ----
        const int bt1 = bid - SEG_CT;      // 0..485
        const int b  = bt1 / 243, t1 = bt1 - b * 243;
        const int t2 = t1 / 27,  t3 = t1 - t2 * 27;
        const int n  = b * 9 + t2;
        __shared__ float logit[17][2];
        __shared__ float aw[17][2];

        if (tid < 34) {
            int p = tid >> 1, o = tid & 1;
            const float* vrow = value + ((long)bt1 * 17 + p) * 128;
            const float* wrow = w_attn + o * 128;
            float s = 0.f;
            for (int c = 0; c < 128; c += 4) {
                float4 v = *(const float4*)(vrow + c);
                float4 w = *(const float4*)(wrow + c);
                s += v.x * w.x + v.y * w.y + v.z * w.z + v.w * w.w;
            }
            logit[p][o] = s + b_attn[o];
        }
        __syncthreads();
        if (tid < 17) {
            float l0 = logit[tid][0], l1 = logit[tid][1];
            float mx = fmaxf(l0, l1);
            float e0 = expf(l0 - mx), e1 = expf(l1 - mx);
            float inv = 1.f / (e0 + e1);
            aw[tid][0] = e0 * inv; aw[tid][1] = e1 * inv;
        }
        __syncthreads();
        for (int j = tid; j < 306; j += 256) {
            int q = j >> 1, o = j & 1;
            const float* qrow = query + ((long)bt1 * 153 + q) * 128;
            const float* wrow = w_off + o * 128;
            float s = 0.f;
            for (int c = 0; c < 128; c += 4) {
                float4 v = *(const float4*)(qrow + c);
                float4 w = *(const float4*)(wrow + c);
                s += v.x * w.x + v.y * w.y + v.z * w.z + v.w * w.w;
            }
            float off = tanhf(s + b_off[o]);
            float sp = off * aw[q % 17][o];
            long kidx = (((long)n * 27 + t3) * 153 + q) * 2 + o;
            samp[kidx] = key[kidx] + sp;
        }
    }
}

// ---------------- gather + mean + blend -> new_query ----------------
// 8 positions/block, 32 lanes/position, 4 channels/lane (float4).
__global__ __launch_bounds__(256) void gather_k(
    const unsigned short* __restrict__ Ebase,
    const float* __restrict__ samp, const float* __restrict__ query,
    const float* __restrict__ be0, const float* __restrict__ be1,
    const float* __restrict__ be2, const float* __restrict__ be3,
    float* __restrict__ nq)
{
    const int tid = threadIdx.x;
    const int pos = blockIdx.x * 8 + (tid >> 5);
    if (pos >= NPOS) return;
    const int c4 = (tid & 31) << 2;
    const int bt1 = pos / 153, q = pos - bt1 * 153;
    const int b  = bt1 / 243, t1 = bt1 - b * 243;
    const int t2 = t1 / 27,  t3 = t1 - t2 * 27;
    const int n  = b * 9 + t2;
    const long sbase = (((long)n * 27 + t3) * 153 + q) * 2;
    const float gx = samp[sbase], gy = samp[sbase + 1];

    float ax = 0.f, ay = 0.f, az = 0.f, aww = 0.f;
    const long Eoffs[4] = {E0_OFF, E1_OFF, E2_OFF, E3_OFF};
    const int Hs[4] = {96, 48, 24, 12}, Wd[4] = {72, 36, 18, 9};
    #pragma unroll
    for (int l = 0; l < 4; ++l) {
        const int H = Hs[l], W = Wd[l];
        const unsigned short* E = Ebase + Eoffs[l] + (long)n * H * W * 128 + c4;
        float ix = ((gx + 1.f) * (float)W - 1.f) * 0.5f;
        float iy = ((gy + 1.f) * (float)H - 1.f) * 0.5f;
        float fx0 = floorf(ix), fy0 = floorf(iy);
        int x0 = (int)fx0, y0 = (int)fy0;
        int x1 = x0 + 1, y1 = y0 + 1;
        float wx1 = ix - fx0, wx0 = 1.f - wx1;
        float wy1 = iy - fy0, wy0 = 1.f - wy1;
        float w00 = wy0 * wx0, w01 = wy0 * wx1, w10 = wy1 * wx0, w11 = wy1 * wx1;
        bool vy0 = (unsigned)y0 < (unsigned)H, vy1 = (unsigned)y1 < (unsigned)H;
        bool vx0 = (unsigned)x0 < (unsigned)W, vx1 = (unsigned)x1 < (unsigned)W;
        if (vy0 && vx0) { ushort4 v = *(const ushort4*)(E + ((long)y0 * W + x0) * 128);
            ax = fmaf(w00, bf2f(v.x), ax); ay = fmaf(w00, bf2f(v.y), ay);
            az = fmaf(w00, bf2f(v.z), az); aww = fmaf(w00, bf2f(v.w), aww); }
        if (vy0 && vx1) { ushort4 v = *(const ushort4*)(E + ((long)y0 * W + x1) * 128);
            ax = fmaf(w01, bf2f(v.x), ax); ay = fmaf(w01, bf2f(v.y), ay);
            az = fmaf(w01, bf2f(v.z), az); aww = fmaf(w01, bf2f(v.w), aww); }
        if (vy1 && vx0) { ushort4 v = *(const ushort4*)(E + ((long)y1 * W + x0) * 128);
            ax = fmaf(w10, bf2f(v.x), ax); ay = fmaf(w10, bf2f(v.y), ay);
            az = fmaf(w10, bf2f(v.z), az); aww = fmaf(w10, bf2f(v.w), aww); }
        if (vy1 && vx1) { ushort4 v = *(const ushort4*)(E + ((long)y1 * W + x1) * 128);
            ax = fmaf(w11, bf2f(v.x), ax); ay = fmaf(w11, bf2f(v.y), ay);
            az = fmaf(w11, bf2f(v.z), az); aww = fmaf(w11, bf2f(v.w), aww); }
    }
    float bsx = be0[c4]     + be1[c4]     + be2[c4]     + be3[c4];
    float bsy = be0[c4 + 1] + be1[c4 + 1] + be2[c4 + 1] + be3[c4 + 1];
    float bsz = be0[c4 + 2] + be1[c4 + 2] + be2[c4 + 2] + be3[c4 + 2];
    float bsw = be0[c4 + 3] + be1[c4 + 3] + be2[c4 + 3] + be3[c4 + 3];
    float mx = 0.25f * (ax + bsx), my = 0.25f * (ay + bsy);
    float mz = 0.25f * (az + bsz), mw = 0.25f * (aww + bsw);
    const long qi = ((long)bt1 * 153 + q) * 128 + c4;
    float4 qv = *(const float4*)(query + qi);
    float4 o;
    o.x = 0.1f * mx + 0.9f * qv.x;
    o.y = 0.1f * my + 0.9f * qv.y;
    o.z = 0.1f * mz + 0.9f * qv.z;
    o.w = 0.1f * mw + 0.9f * qv.w;
    *(float4*)(nq + qi) = o;
}

// ---------------- conv GEMM via bf16 MFMA ----------------
// nv[m][o] = sum_kk nq[m*1152+kk] * convT2[o][kk] + conv_b[o]
// grid (259 m-tiles, 2 n-tiles); block 256 = 4 waves (2x2);
// tile M=32 x N=64, BK=32; register double-buffer. 518 blocks for latency hiding.
__global__ __launch_bounds__(256) void conv_mfma_k(
    const float* __restrict__ nq, const unsigned short* __restrict__ convT2,
    const float* __restrict__ conv_b, float* __restrict__ nv)
{
    __shared__ unsigned short As[32][40];   // [m][k] pad 32->40
    __shared__ unsigned short Bs[64][40];   // [n][k]

    const int tid  = threadIdx.x;
    const int lane = tid & 63;
    const int wave = tid >> 6;
    const int wm = (wave & 1) * 16;
    const int wn = (wave >> 1) * 32;
    const int m0 = blockIdx.x * 32;
    const int n0 = blockIdx.y * 64;
    const int l15  = lane & 15;
    const int quad = lane >> 4;

    floatx4 acc[2];
    acc[0] = (floatx4){0.f, 0.f, 0.f, 0.f};
    acc[1] = acc[0];

    const int am = tid >> 3;             // 0..31
    const int ak = (tid & 7) << 2;       // 0,4,..,28
    const int bn = tid >> 2;             // 0..63
    const int bk = (tid & 3) << 3;       // 0,8,16,24

    float4 a0; uint4 bv;
    auto fetch = [&](int k0) {
        a0 = (float4){0,0,0,0};
        int row = m0 + am;
        if (row < M_CONV)
            a0 = *(const float4*)(nq + (long)row * 1152 + k0 + ak);
        bv = *(const uint4*)(convT2 + (long)(n0 + bn) * 1152 + k0 + bk);
    };
    fetch(0);

    for (int k0 = 0; k0 < 1152; k0 += 32) {
        unsigned short t[4] = {f2bf_rne(a0.x), f2bf_rne(a0.y), f2bf_rne(a0.z), f2bf_rne(a0.w)};
        *(uint2*)&As[am][ak] = *(const uint2*)t;
        *(uint4*)&Bs[bn][bk] = bv;
        __syncthreads();
        if (k0 + 32 < 1152) fetch(k0 + 32);

        short8 af = *(const short8*)&As[wm + l15][quad * 8];
        #pragma unroll
        for (int nt = 0; nt < 2; ++nt) {
            short8 bf = *(const short8*)&Bs[wn + nt * 16 + l15][quad * 8];
            acc[nt] = __builtin_amdgcn_mfma_f32_16x16x32_bf16(af, bf, acc[nt], 0, 0, 0);
        }
        __syncthreads();
    }

    // epilogue: C/D layout col=lane&15, row=quad*4+r
    #pragma unroll
    for (int nt = 0; nt < 2; ++nt) {
        int col = n0 + wn + nt * 16 + l15;
        float bias = conv_b[col];
        #pragma unroll
        for (int r = 0; r < 4; ++r) {
            int row = m0 + wm + quad * 4 + r;
            if (row < M_CONV)
                nv[(long)row * 128 + col] = acc[nt][r] + bias;
        }
    }
}

extern "C" void kernel_launch(void* const* d_in, const int* in_sizes, int n_in,
                              void* d_out, int out_size, void* d_ws, size_t ws_size,
                              hipStream_t stream) {
    const float* f0     = (const float*)d_in[0];
    const float* f1     = (const float*)d_in[1];
    const float* f2     = (const float*)d_in[2];
    const float* f3     = (const float*)d_in[3];
    const float* query  = (const float*)d_in[4];
    const float* key    = (const float*)d_in[5];
    const float* value  = (const float*)d_in[6];
    const float* w_off  = (const float*)d_in[7];
    const float* b_off  = (const float*)d_in[8];
    const float* w_attn = (const float*)d_in[9];
    const float* b_attn = (const float*)d_in[10];
    const float* we0    = (const float*)d_in[11];
    const float* be0    = (const float*)d_in[12];
    const float* we1    = (const float*)d_in[13];
    const float* be1    = (const float*)d_in[14];
    const float* we2    = (const float*)d_in[15];
    const float* be2    = (const float*)d_in[16];
    const float* we3    = (const float*)d_in[17];
    const float* be3    = (const float*)d_in[18];
    const float* conv_w = (const float*)d_in[19];
    const float* conv_b = (const float*)d_in[20];

    float* out  = (float*)d_out;
    float* nq   = out;                       // new_query
    float* nv   = out + NQ_SIZE;             // new_value
    float* samp = out + NQ_SIZE + NV_SIZE;   // sampling_positions

    // ws layout: E maps (bf16, 21,150,720) | convT2 (bf16, 147,456)
    unsigned short* Ebase  = (unsigned short*)d_ws;
    unsigned short* convT2 = Ebase + E_END;

    // 1. fused prep: projections (MFMA, chunked-B LDS) + convT2 + sampling positions
    prep_k<<<PREP_GRID, 256, 0, stream>>>(
        f0, f1, f2, f3, we0, we1, we2, we3, conv_w, convT2,
        query, value, key, w_off, b_off, w_attn, b_attn, samp, Ebase);

    // 2. gather + mean + blend -> new_query (9295 blocks)
    gather_k<<<(NPOS + 7) / 8, 256, 0, stream>>>(Ebase, samp, query, be0, be1, be2, be3, nq);

    // 3. new_value GEMM via MFMA: M=8262, K=1152, N=128 (518 blocks)
    conv_mfma_k<<<dim3(259, 2), 256, 0, stream>>>(nq, convT2, conv_b, nv);
}